// Round 8
// baseline (88.055 us; speedup 1.0000x reference)
//
#include <hip/hip_runtime.h>
#include <hip/hip_bf16.h>
#include <hip/hip_fp16.h>

#define B_SZ 1024
#define T_LEN 8192
#define NBINS 819            // T//10
#define PSD_LDA 1664         // padded bf16 row stride (zero-padded 1638..1663)
#define PI_F 3.14159265358979323846f

typedef __attribute__((ext_vector_type(8))) short bf16x8;
typedef __attribute__((ext_vector_type(4))) float f32x4;

// ---- compile-time FFT tables ----------------------------------------------
__device__ constexpr float C32T[16] = {
  1.0f, 0.980785280f, 0.923879533f, 0.831469612f, 0.707106781f, 0.555570233f,
  0.382683432f, 0.195090322f, 0.0f, -0.195090322f, -0.382683432f, -0.555570233f,
  -0.707106781f, -0.831469612f, -0.923879533f, -0.980785280f};
__device__ constexpr float S32T[16] = {   // -sin(2*pi*k/32)
  0.0f, -0.195090322f, -0.382683432f, -0.555570233f, -0.707106781f,
  -0.831469612f, -0.923879533f, -0.980785280f, -1.0f, -0.980785280f,
  -0.923879533f, -0.831469612f, -0.707106781f, -0.555570233f, -0.382683432f,
  -0.195090322f};
__device__ constexpr int BR5[32] = {   // 5-bit bit-reverse
  0,16,8,24,4,20,12,28,2,18,10,26,6,22,14,30,
  1,17,9,25,5,21,13,29,3,19,11,27,7,23,15,31};
__device__ constexpr float E8C[8] = {  // cos(pi*c/4)  (W_8^{7c} = e^{+i pi c/4})
  1.0f, 0.707106781f, 0.0f, -0.707106781f, -1.0f, -0.707106781f, 0.0f, 0.707106781f};
__device__ constexpr float E8S[8] = {  // sin(pi*c/4)
  0.0f, 0.707106781f, 1.0f, 0.707106781f, 0.0f, -0.707106781f, -1.0f, -0.707106781f};

template<int S>
__device__ __forceinline__ void fft32_stage(float (&xr)[32], float (&xi)[32]) {
  #pragma unroll
  for (int o = 0; o < 32; o += 2 * S) {
    #pragma unroll
    for (int j = 0; j < S; ++j) {
      const int i0 = o + j, i1 = o + j + S;
      float ur = xr[i0] + xr[i1], ui = xi[i0] + xi[i1];
      float dr = xr[i0] - xr[i1], di = xi[i0] - xi[i1];
      const float c = C32T[j * (16 / S)], sn = S32T[j * (16 / S)];
      xr[i0] = ur; xi[i0] = ui;
      xr[i1] = dr * c - di * sn;
      xi[i1] = dr * sn + di * c;
    }
  }
}
__device__ __forceinline__ void fft32(float (&xr)[32], float (&xi)[32]) {
  fft32_stage<16>(xr, xi); fft32_stage<8>(xr, xi); fft32_stage<4>(xr, xi);
  fft32_stage<2>(xr, xi);  fft32_stage<1>(xr, xi);
  // X[k] sits at register index BR5[k]
}

// ---------------------------------------------------------------------------
// Kernel 1: normalize feature rows (B x 256) -> bf16
// ---------------------------------------------------------------------------
__global__ __launch_bounds__(256) void normalize_kernel(
    const float* __restrict__ f, __hip_bfloat16* __restrict__ fn) {
  int i = blockIdx.x;
  int t = threadIdx.x;
  float v = f[(size_t)i * 256 + t];
  float s = v * v;
  #pragma unroll
  for (int o = 32; o; o >>= 1) s += __shfl_down(s, o);
  __shared__ float buf[4];
  if ((t & 63) == 0) buf[t >> 6] = s;
  __syncthreads();
  float norm = sqrtf(buf[0] + buf[1] + buf[2] + buf[3]);
  norm = fmaxf(norm, 1e-12f);
  fn[(size_t)i * 256 + t] = __float2bfloat16(v / norm);
}

// ---------------------------------------------------------------------------
// Kernel 2a: FFT stage 1. One block per trajectory, NO data LDS, 1 barrier.
// n = 256a + 8b + c (tid = 8b+c); k = k0 + 32k1 + 1024k2.
// Load y,w -> sums -> Hann -> FFT32 over a -> *W_8192^{tid*k0}
//  -> global write t1[traj][k0][c][b] (half2). Also vmean + winding.
// ---------------------------------------------------------------------------
__global__ __launch_bounds__(256) void traj_fft1_kernel(
    const float* __restrict__ trajf,
    __half2* __restrict__ t1,
    float2* __restrict__ vmean,
    float2* __restrict__ wind) {
  __shared__ float rsum[2][4];
  __shared__ float phb[4];

  const int tid = threadIdx.x;
  const float* rowf = trajf + (size_t)blockIdx.x * T_LEN * 4;
  const int b = tid >> 3, c = tid & 7;
  __half2* t1row = t1 + (size_t)blockIdx.x * T_LEN;

  float xr[32], xi[32];
  float sum0 = 0.f, sum1 = 0.f;
  const float wstep = 2.0f * PI_F / (float)T_LEN;

  // ---- load y,w channels straight into the data arrays (64 loads in flight)
  #pragma unroll
  for (int a = 0; a < 32; ++a) {
    const size_t base = (size_t)4 * (a * 256 + tid);
    xr[a] = rowf[base + 1];
    xi[a] = rowf[base + 3];
  }
  if (tid == 0) {   // phase endpoints
    phb[0] = rowf[0];
    phb[1] = rowf[2];
    phb[2] = rowf[(size_t)4 * (T_LEN - 1)];
    phb[3] = rowf[(size_t)4 * (T_LEN - 1) + 2];
  }

  // ---- sums + Hann window in-place
  #pragma unroll
  for (int a = 0; a < 32; ++a) {
    sum0 += xr[a]; sum1 += xi[a];
    float w = 0.5f * (1.0f - __cosf(wstep * (float)(a * 256 + tid)));
    xr[a] *= w;
    xi[a] *= w;
  }

  // ---- stage 1: FFT32 over a
  fft32(xr, xi);

  // ---- twiddle W_8192^{tid*k0} fused with global T1 write: [k0][c][b]
  {
    float s1, c1, s16, c16;
    __sincosf(-2.0f * PI_F * (float)tid / 8192.0f, &s1, &c1);
    __sincosf(-2.0f * PI_F * (float)tid / 512.0f,  &s16, &c16);
    float wr0 = 1.f, wi0 = 0.f, wr1 = c16, wi1 = s16;
    #pragma unroll
    for (int k0 = 0; k0 < 16; ++k0) {
      {
        const int r = BR5[k0];
        float tr = xr[r] * wr0 - xi[r] * wi0;
        float ti = xr[r] * wi0 + xi[r] * wr0;
        t1row[k0 * 256 + c * 32 + b] = __floats2half2_rn(tr, ti);
        float nr = wr0 * c1 - wi0 * s1; wi0 = wr0 * s1 + wi0 * c1; wr0 = nr;
      }
      {
        const int k0b = k0 + 16;
        const int r = BR5[k0b];
        float tr = xr[r] * wr1 - xi[r] * wi1;
        float ti = xr[r] * wi1 + xi[r] * wr1;
        t1row[k0b * 256 + c * 32 + b] = __floats2half2_rn(tr, ti);
        float nr = wr1 * c1 - wi1 * s1; wi1 = wr1 * s1 + wi1 * c1; wr1 = nr;
      }
    }
  }

  // ---- v_mean and winding
  #pragma unroll
  for (int o = 32; o; o >>= 1) {
    sum0 += __shfl_down(sum0, o);
    sum1 += __shfl_down(sum1, o);
  }
  if ((tid & 63) == 0) { rsum[0][tid >> 6] = sum0; rsum[1][tid >> 6] = sum1; }
  __syncthreads();
  if (tid == 0) {
    float s0 = rsum[0][0] + rsum[0][1] + rsum[0][2] + rsum[0][3];
    float s1v = rsum[1][0] + rsum[1][1] + rsum[1][2] + rsum[1][3];
    vmean[blockIdx.x] = make_float2(s0 / (float)T_LEN, s1v / (float)T_LEN);
    const float inv2pi = 0.15915494309189535f;
    wind[blockIdx.x] = make_float2(fabsf(rintf((phb[2] - phb[0]) * inv2pi)),
                                   fabsf(rintf((phb[3] - phb[1]) * inv2pi)));
  }
}

// ---------------------------------------------------------------------------
// Kernel 2b: FFT stages 2+3 + psd. One block per trajectory, 32 KB LDS,
// 3 barriers. Thread (k0r,cr) reads t1[k0r][cr][b] coalesced as 16B loads.
// ---------------------------------------------------------------------------
__global__ __launch_bounds__(256) void traj_fft2_kernel(
    const __half2* __restrict__ t1,
    __hip_bfloat16* __restrict__ psd) {
  __shared__ __half2 z2[T_LEN];   // 32 KB

  const int tid = threadIdx.x;
  const int k0r = tid >> 3, cr = tid & 7;
  const __half2* t1row = t1 + (size_t)blockIdx.x * T_LEN;

  float xr[32], xi[32];

  // ---- coalesced read of T1: 8 x 16B per thread, b-contiguous
  #pragma unroll
  for (int q = 0; q < 8; ++q) {
    float4 v4 = *(const float4*)(t1row + k0r * 256 + cr * 32 + 4 * q);
    __half2 h0 = *(__half2*)&v4.x, h1 = *(__half2*)&v4.y;
    __half2 h2 = *(__half2*)&v4.z, h3 = *(__half2*)&v4.w;
    xr[4*q+0] = __low2float(h0); xi[4*q+0] = __high2float(h0);
    xr[4*q+1] = __low2float(h1); xi[4*q+1] = __high2float(h1);
    xr[4*q+2] = __low2float(h2); xi[4*q+2] = __high2float(h2);
    xr[4*q+3] = __low2float(h3); xi[4*q+3] = __high2float(h3);
  }

  // ---- stage 2: FFT32 over b
  fft32(xr, xi);

  // ---- twiddle W_256^{cr*k1} fused with T2 write
  // T2 word(p,c) = p*8 + (c ^ ((p>>2)&7)), p = k1*32 + k0r
  {
    float s1, c1, s16, c16;
    __sincosf(-2.0f * PI_F * (float)cr / 256.0f, &s1, &c1);
    __sincosf(-2.0f * PI_F * (float)cr / 16.0f,  &s16, &c16);
    float wr0 = 1.f, wi0 = 0.f, wr1 = c16, wi1 = s16;
    #pragma unroll
    for (int k1 = 0; k1 < 16; ++k1) {
      {
        const int r = BR5[k1];
        const int p = (k1 << 5) + k0r;
        float tr = xr[r] * wr0 - xi[r] * wi0;
        float ti = xr[r] * wi0 + xi[r] * wr0;
        z2[(p << 3) + (cr ^ ((p >> 2) & 7))] = __floats2half2_rn(tr, ti);
        float nr = wr0 * c1 - wi0 * s1; wi0 = wr0 * s1 + wi0 * c1; wr0 = nr;
      }
      {
        const int k1b = k1 + 16;
        const int r = BR5[k1b];
        const int p = (k1b << 5) + k0r;
        float tr = xr[r] * wr1 - xi[r] * wi1;
        float ti = xr[r] * wi1 + xi[r] * wr1;
        z2[(p << 3) + (cr ^ ((p >> 2) & 7))] = __floats2half2_rn(tr, ti);
        float nr = wr1 * c1 - wi1 * s1; wi1 = wr1 * s1 + wi1 * c1; wr1 = nr;
      }
    }
  }
  __syncthreads();

  // ---- stage 3: partial DFT8 over c; 4 p-values per thread, k2 in {0,7}
  float z0r[4], z0i[4], z7r[4], z7i[4];
  #pragma unroll
  for (int q = 0; q < 4; ++q) {
    const int p = q * 256 + tid;
    float s0r = 0.f, s0i = 0.f, s7r = 0.f, s7i = 0.f;
    #pragma unroll
    for (int c2 = 0; c2 < 8; ++c2) {
      __half2 v = z2[(p << 3) + (c2 ^ ((p >> 2) & 7))];
      float vr = __low2float(v), vi = __high2float(v);
      s0r += vr; s0i += vi;
      s7r += vr * E8C[c2] - vi * E8S[c2];
      s7i += vr * E8S[c2] + vi * E8C[c2];
    }
    z0r[q] = s0r; z0i[q] = s0i; z7r[q] = s7r; z7i[q] = s7i;
  }
  __syncthreads();   // all stage-3 reads done
  float2* zf = (float2*)z2;   // fp32 result region: 2048 float2 = 16 KB
  #pragma unroll
  for (int q = 0; q < 4; ++q) {
    const int p = q * 256 + tid;
    zf[p]        = make_float2(z0r[q], z0i[q]);   // Z[p], p in [0,1024)
    zf[1024 + p] = make_float2(z7r[q], z7i[q]);   // Z[7168+p]
  }
  __syncthreads();

  // ---- unpack packed real FFTs -> psd (bf16), zero-pad to PSD_LDA
  for (int k = tid; k < PSD_LDA / 2; k += 256) {
    if (k < NBINS) {
      float2 Zk = zf[k];
      float2 Zn = (k == 0) ? zf[0] : zf[2048 - k];   // Z[8192-k]
      float fxr = 0.5f * (Zk.x + Zn.x);
      float fxi = 0.5f * (Zk.y - Zn.y);
      float fyr = 0.5f * (Zk.y + Zn.y);
      float fyi = 0.5f * (Zn.x - Zk.x);
      psd[(size_t)blockIdx.x * PSD_LDA + 2*k]     = __float2bfloat16(fxr*fxr + fxi*fxi);
      psd[(size_t)blockIdx.x * PSD_LDA + 2*k + 1] = __float2bfloat16(fyr*fyr + fyi*fyi);
    } else {
      psd[(size_t)blockIdx.x * PSD_LDA + 2*k]     = __float2bfloat16(0.0f);
      psd[(size_t)blockIdx.x * PSD_LDA + 2*k + 1] = __float2bfloat16(0.0f);
    }
  }
}

// ---------------------------------------------------------------------------
// Kernel 3: C = A * A^T, A (1024 x K bf16, stride LDA), MFMA 16x16x32 bf16.
// ---------------------------------------------------------------------------
template<int K, int LDA>
__global__ __launch_bounds__(256) void gram_mfma_kernel(
    const __hip_bfloat16* __restrict__ A, float* __restrict__ C) {
  __shared__ __align__(16) __hip_bfloat16 lds[2][64][64];  // 16 KB
  const int tid  = threadIdx.x;
  const int lane = tid & 63;
  const int wave = tid >> 6;
  const int wm = wave >> 1, wn = wave & 1;
  const int i0 = blockIdx.y * 64;
  const int j0 = blockIdx.x * 64;

  f32x4 acc[2][2] = {};

  for (int k0 = 0; k0 < K; k0 += 64) {
    #pragma unroll
    for (int r = 0; r < 2; ++r) {
      int e   = tid + 256 * r;
      int row = e >> 3;
      int cb  = e & 7;
      int scb = cb ^ (row & 7);
      const __hip_bfloat16* srcA = A + (size_t)(i0 + row) * LDA + k0 + scb * 8;
      const __hip_bfloat16* srcB = A + (size_t)(j0 + row) * LDA + k0 + scb * 8;
      __builtin_amdgcn_global_load_lds(
          (const __attribute__((address_space(1))) void*)srcA,
          (__attribute__((address_space(3))) void*)(&lds[0][0][0] + e * 8),
          16, 0, 0);
      __builtin_amdgcn_global_load_lds(
          (const __attribute__((address_space(1))) void*)srcB,
          (__attribute__((address_space(3))) void*)(&lds[1][0][0] + e * 8),
          16, 0, 0);
    }
    __syncthreads();

    #pragma unroll
    for (int ks = 0; ks < 2; ++ks) {
      bf16x8 afr[2], bfr[2];
      #pragma unroll
      for (int m = 0; m < 2; ++m) {
        int row = wm * 32 + m * 16 + (lane & 15);
        int cidx = ks * 4 + (lane >> 4);
        int cc  = cidx ^ (row & 7);
        afr[m] = *(const bf16x8*)(&lds[0][row][cc * 8]);
      }
      #pragma unroll
      for (int n = 0; n < 2; ++n) {
        int row = wn * 32 + n * 16 + (lane & 15);
        int cidx = ks * 4 + (lane >> 4);
        int cc  = cidx ^ (row & 7);
        bfr[n] = *(const bf16x8*)(&lds[1][row][cc * 8]);
      }
      #pragma unroll
      for (int m = 0; m < 2; ++m)
        #pragma unroll
        for (int n = 0; n < 2; ++n)
          acc[m][n] = __builtin_amdgcn_mfma_f32_16x16x32_bf16(
              afr[m], bfr[n], acc[m][n], 0, 0, 0);
    }
    __syncthreads();
  }

  #pragma unroll
  for (int m = 0; m < 2; ++m)
    #pragma unroll
    for (int n = 0; n < 2; ++n)
      #pragma unroll
      for (int r = 0; r < 4; ++r) {
        int row = i0 + wm * 32 + m * 16 + (lane >> 4) * 4 + r;
        int col = j0 + wn * 32 + n * 16 + (lane & 15);
        C[(size_t)row * B_SZ + col] = acc[m][n][r];
      }
}

// ---------------------------------------------------------------------------
// Kernel 4: per-row loss. One block per row i.
// ---------------------------------------------------------------------------
__global__ __launch_bounds__(256) void loss_rows_kernel(
    const float* __restrict__ S,
    const float* __restrict__ G,
    const float* __restrict__ labels,
    const float* __restrict__ scales,
    const float2* __restrict__ vmean,
    const float2* __restrict__ wind,
    float* __restrict__ row_loss) {
  const int i = blockIdx.x;
  const int tid = threadIdx.x;
  const float inv_scale = 1.0f / scales[0];
  const float l0 = labels[i*3+0], l1 = labels[i*3+1], l2 = labels[i*3+2];
  const float2 vmi = vmean[i];
  const float2 wi  = wind[i];
  const float n2i  = G[(size_t)i * B_SZ + i];
  const float normi = sqrtf(n2i);

  float posw = 0.f, den = 0.f;
  for (int j = tid; j < B_SZ; j += 256) {
    if (j == i) continue;
    float e = __expf(S[(size_t)i * B_SZ + j] * 10.0f);
    den += e;

    float d0 = (labels[j*3+0] - l0) * inv_scale;
    float d1 = (labels[j*3+1] - l1) * inv_scale;
    float d2v = (labels[j*3+2] - l2) * inv_scale;
    float pd = sqrtf(d0*d0 + d1*d1 + d2v*d2v);
    float pw = __expf(-pd * 10.0f);

    float2 vmj = vmean[j];
    float dvx = vmi.x - vmj.x, dvy = vmi.y - vmj.y;
    float v_sim = __expf(-sqrtf(dvx*dvx + dvy*dvy) * 2.0f);

    float n2j = G[(size_t)j * B_SZ + j];
    float g   = G[(size_t)i * B_SZ + j];
    float dd  = fmaxf(n2i + n2j - 2.0f * g, 0.0f);
    float psd_dist = sqrtf(dd);
    float norma = (i < j) ? normi : sqrtf(n2j);
    float psd_sim = __expf(-psd_dist / (norma + 1e-8f));

    float2 wj = wind[j];
    float w_sim = (wi.x == wj.x && wi.y == wj.y) ? 1.0f : 0.0f;

    float kin = 0.4f * v_sim + 0.4f * psd_sim + 0.2f * w_sim;
    posw += e * pw * kin;
  }

  #pragma unroll
  for (int o = 32; o; o >>= 1) {
    posw += __shfl_down(posw, o);
    den  += __shfl_down(den, o);
  }
  __shared__ float bp[4], bd[4];
  if ((tid & 63) == 0) { bp[tid >> 6] = posw; bd[tid >> 6] = den; }
  __syncthreads();
  if (tid == 0) {
    float P = bp[0] + bp[1] + bp[2] + bp[3];
    float D = bd[0] + bd[1] + bd[2] + bd[3];
    row_loss[i] = -logf((P + 1e-8f) / (D + 1e-8f));
  }
}

// ---------------------------------------------------------------------------
// Kernel 5: mean of row losses -> scalar
// ---------------------------------------------------------------------------
__global__ __launch_bounds__(256) void reduce_mean_kernel(
    const float* __restrict__ row_loss, float* __restrict__ out) {
  int tid = threadIdx.x;
  float s = 0.f;
  for (int i = tid; i < B_SZ; i += 256) s += row_loss[i];
  #pragma unroll
  for (int o = 32; o; o >>= 1) s += __shfl_down(s, o);
  __shared__ float buf[4];
  if ((tid & 63) == 0) buf[tid >> 6] = s;
  __syncthreads();
  if (tid == 0) out[0] = (buf[0] + buf[1] + buf[2] + buf[3]) / (float)B_SZ;
}

// ---------------------------------------------------------------------------
extern "C" void kernel_launch(void* const* d_in, const int* in_sizes, int n_in,
                              void* d_out, int out_size, void* d_ws, size_t ws_size,
                              hipStream_t stream) {
  const float* features = (const float*)d_in[0];
  const float* labels   = (const float*)d_in[1];
  const float* traj     = (const float*)d_in[2];
  const float* scales   = (const float*)d_in[3];

  char* ws = (char*)d_ws;
  __hip_bfloat16* f_n = (__hip_bfloat16*)ws;                                 // 0.5 MB
  __hip_bfloat16* psd = (__hip_bfloat16*)(ws + (size_t)B_SZ*256*2);          // 3.25 MB
  float* G = (float*)(ws + (size_t)B_SZ*256*2 + (size_t)B_SZ*PSD_LDA*2);     // 4 MB
  float* S = G + (size_t)B_SZ * B_SZ;                                        // 4 MB
  float2* vmean = (float2*)(S + (size_t)B_SZ * B_SZ);
  float2* wind  = vmean + B_SZ;
  float* row_loss = (float*)(wind + B_SZ);
  // 16B-aligned 32 MB T1 intermediate
  __half2* t1 = (__half2*)(ws + ((((size_t)B_SZ*256*2 + (size_t)B_SZ*PSD_LDA*2
                 + 2*(size_t)B_SZ*B_SZ*4 + B_SZ*16 + B_SZ*4) + 255) & ~(size_t)255));

  normalize_kernel<<<B_SZ, 256, 0, stream>>>(features, f_n);
  traj_fft1_kernel<<<B_SZ, 256, 0, stream>>>(traj, t1, vmean, wind);
  traj_fft2_kernel<<<B_SZ, 256, 0, stream>>>(t1, psd);

  dim3 grid16(16, 16);
  gram_mfma_kernel<PSD_LDA, PSD_LDA><<<grid16, 256, 0, stream>>>(psd, G);
  gram_mfma_kernel<256, 256><<<grid16, 256, 0, stream>>>(f_n, S);

  loss_rows_kernel<<<B_SZ, 256, 0, stream>>>(S, G, labels, scales, vmean, wind, row_loss);
  reduce_mean_kernel<<<1, 256, 0, stream>>>(row_loss, (float*)d_out);
}

// Round 9
// 69.131 us; speedup vs baseline: 1.2737x; 1.2737x over previous
//
#include <hip/hip_runtime.h>
#include <hip/hip_bf16.h>

#define B_SZ 1024
#define T_LEN 8192
#define NBINS 819            // T//10
#define PSD_LDA 1664         // padded bf16 row stride (zero-padded 1638..1663)
#define PI_F 3.14159265358979323846f

typedef __attribute__((ext_vector_type(8))) short bf16x8;
typedef __attribute__((ext_vector_type(4))) float f32x4;

// ---- tables ---------------------------------------------------------------
__device__ constexpr float W32C[32] = {   // cos(2*pi*m/32)
  1.0f, 0.980785280f, 0.923879533f, 0.831469612f, 0.707106781f, 0.555570233f,
  0.382683432f, 0.195090322f, 0.0f, -0.195090322f, -0.382683432f, -0.555570233f,
  -0.707106781f, -0.831469612f, -0.923879533f, -0.980785280f, -1.0f,
  -0.980785280f, -0.923879533f, -0.831469612f, -0.707106781f, -0.555570233f,
  -0.382683432f, -0.195090322f, 0.0f, 0.195090322f, 0.382683432f, 0.555570233f,
  0.707106781f, 0.831469612f, 0.923879533f, 0.980785280f};
__device__ constexpr float W32S[32] = {   // -sin(2*pi*m/32)
  0.0f, -0.195090322f, -0.382683432f, -0.555570233f, -0.707106781f,
  -0.831469612f, -0.923879533f, -0.980785280f, -1.0f, -0.980785280f,
  -0.923879533f, -0.831469612f, -0.707106781f, -0.555570233f, -0.382683432f,
  -0.195090322f, 0.0f, 0.195090322f, 0.382683432f, 0.555570233f, 0.707106781f,
  0.831469612f, 0.923879533f, 0.980785280f, 1.0f, 0.980785280f, 0.923879533f,
  0.831469612f, 0.707106781f, 0.555570233f, 0.382683432f, 0.195090322f};
__device__ constexpr float E8C[8] = {  // cos(pi*c/4)
  1.0f, 0.707106781f, 0.0f, -0.707106781f, -1.0f, -0.707106781f, 0.0f, 0.707106781f};
__device__ constexpr float E8S[8] = {  // sin(pi*c/4)
  0.0f, 0.707106781f, 1.0f, 0.707106781f, 0.0f, -0.707106781f, -1.0f, -0.707106781f};

__device__ __forceinline__ unsigned short bfb(float x) {
  __hip_bfloat16 h = __float2bfloat16(x);
  return *(unsigned short*)&h;
}
__device__ __forceinline__ float bff(unsigned short u) {
  union { unsigned u; float f; } v; v.u = ((unsigned)u) << 16; return v.f;
}
__device__ __forceinline__ unsigned packbf(float r, float i) {
  return (unsigned)bfb(r) | ((unsigned)bfb(i) << 16);
}

// LDS word index for X1[k0][b][c]: strides chosen so banks spread over g and c
#define WIDX(k0, b, c) ((k0) * 288 + 9 * (b) + (c))

// ---------------------------------------------------------------------------
// Kernel 1: normalize feature rows (B x 256) -> bf16
// ---------------------------------------------------------------------------
__global__ __launch_bounds__(256) void normalize_kernel(
    const float* __restrict__ f, __hip_bfloat16* __restrict__ fn) {
  int i = blockIdx.x;
  int t = threadIdx.x;
  float v = f[(size_t)i * 256 + t];
  float s = v * v;
  #pragma unroll
  for (int o = 32; o; o >>= 1) s += __shfl_down(s, o);
  __shared__ float buf[4];
  if ((t & 63) == 0) buf[t >> 6] = s;
  __syncthreads();
  float norm = sqrtf(buf[0] + buf[1] + buf[2] + buf[3]);
  norm = fmaxf(norm, 1e-12f);
  fn[(size_t)i * 256 + t] = __float2bfloat16(v / norm);
}

// ---------------------------------------------------------------------------
// Kernel 2: per-trajectory stats; DFT32 stages done on the MATRIX pipe.
// 8192 = 32(a) x 32(b) x 8(c); n = 256a + 8b + c; k = k0 + 32k1 + 1024k2.
// Stage1: X1[k0][n] = mfma(W32, x[a][n]) * W_8192^{n k0}   (bf16 MFMA)
// Stage2: X2[k1][k0,c] = mfma(W32, X1[k0][8b+c] over b) * W_256^{c k1}
// Stage3: DFT8 over c (VALU), k2 in {0,7}; psd unpack.
// One block = 1 traj, 256 thr = 4 waves; wave w owns columns [64w, 64w+64).
// ---------------------------------------------------------------------------
__global__ __launch_bounds__(256) void traj_stats_kernel(
    const float* __restrict__ trajf,
    __hip_bfloat16* __restrict__ psd,
    float2* __restrict__ vmean,
    float2* __restrict__ wind) {
  __shared__ unsigned z2w[9216];   // 36 KB: packed (bf16 r | bf16 i)
  __shared__ float rsum[2][4];
  __shared__ float phb[4];

  const int tid = threadIdx.x;
  const int w   = tid >> 6;
  const int l   = tid & 63;
  const int g   = l >> 4;     // k-chunk group within wave (MFMA fragment rule)
  const int lc  = l & 15;     // column-within-tile / m-within-Mtile
  const float* rowf = trajf + (size_t)blockIdx.x * T_LEN * 4;

  if (tid == 0) {
    phb[0] = rowf[0]; phb[1] = rowf[2];
    phb[2] = rowf[(size_t)4 * (T_LEN - 1)];
    phb[3] = rowf[(size_t)4 * (T_LEN - 1) + 2];
  }

  // ---- A fragments: DFT32 matrix W^(mk), lane holds m = mt*16+lc, k = g*8+j
  bf16x8 Ac[2], As[2], Asn[2];
  #pragma unroll
  for (int mt = 0; mt < 2; ++mt) {
    const int m = mt * 16 + lc;
    #pragma unroll
    for (int j = 0; j < 8; ++j) {
      const int idx = (m * (g * 8 + j)) & 31;
      unsigned short uc = bfb(W32C[idx]);   // cos(theta), theta = -2pi idx/32
      unsigned short us = bfb(W32S[idx]);   // sin(theta)
      Ac[mt][j]  = (short)uc;
      As[mt][j]  = (short)us;
      Asn[mt][j] = (short)(us ^ 0x8000);    // -sin(theta)
    }
  }

  float vs0 = 0.f, vs1 = 0.f;
  const f32x4 az = {0.f, 0.f, 0.f, 0.f};

  // ================= stage 1: DFT32 over a (4 column-tiles per wave) =======
  #pragma unroll
  for (int nt = 0; nt < 4; ++nt) {
    const int n = w * 64 + nt * 16 + lc;
    float yr[8], yw[8];
    #pragma unroll
    for (int j = 0; j < 8; ++j) {
      const size_t t = (size_t)(g * 8 + j) * 256 + n;
      yr[j] = rowf[4 * t + 1];
      yw[j] = rowf[4 * t + 3];
    }
    #pragma unroll
    for (int j = 0; j < 8; ++j) { vs0 += yr[j]; vs1 += yw[j]; }
    // hann(t) = 0.5 - 0.5 cos(theta0 + j*pi/16), theta0 = 2pi n/8192 + g*pi/2
    float s0, c0;
    __sincosf(2.0f * PI_F * ((float)n / 8192.0f + (float)g * 0.25f), &s0, &c0);
    bf16x8 xrb, xib;
    #pragma unroll
    for (int j = 0; j < 8; ++j) {
      float wv = 0.5f - 0.5f * (c0 * W32C[j] + s0 * W32S[j]);
      xrb[j] = (short)bfb(yr[j] * wv);
      xib[j] = (short)bfb(yw[j] * wv);
    }
    const int bw = 9 * (n >> 3) + (n & 7);   // per-lane LDS column offset
    #pragma unroll
    for (int mt = 0; mt < 2; ++mt) {
      f32x4 ar = __builtin_amdgcn_mfma_f32_16x16x32_bf16(Asn[mt], xib, az, 0, 0, 0);
      ar = __builtin_amdgcn_mfma_f32_16x16x32_bf16(Ac[mt], xrb, ar, 0, 0, 0);
      f32x4 ai = __builtin_amdgcn_mfma_f32_16x16x32_bf16(Ac[mt], xib, az, 0, 0, 0);
      ai = __builtin_amdgcn_mfma_f32_16x16x32_bf16(As[mt], xrb, ai, 0, 0, 0);
      // twiddle W_8192^{n k0}, k0 = mt*16 + g*4 + r, then LDS write
      float sb, cb, ss, cs;
      const float nf = (float)n;
      __sincosf(-2.0f * PI_F * nf * (float)(mt * 16 + g * 4) / 8192.0f, &sb, &cb);
      __sincosf(-2.0f * PI_F * nf / 8192.0f, &ss, &cs);
      #pragma unroll
      for (int r = 0; r < 4; ++r) {
        float xr_ = ar[r] * cb - ai[r] * sb;
        float xi_ = ar[r] * sb + ai[r] * cb;
        const int k0 = mt * 16 + g * 4 + r;
        z2w[k0 * 288 + bw] = packbf(xr_, xi_);
        float nc = cb * cs - sb * ss; sb = cb * ss + sb * cs; cb = nc;
      }
    }
  }
  __syncthreads();

  // ================= stage 2: DFT32 over b =================================
  unsigned x2_0[2][4], x2_1[2][4], x2_2[2][4], x2_3[2][4];  // [mt][r] per nt
  #pragma unroll
  for (int nt = 0; nt < 4; ++nt) {
    const int n2 = w * 64 + nt * 16 + lc;   // column = (k0, c) pair
    const int k0 = n2 >> 3, cc = n2 & 7;
    bf16x8 xrb, xib;
    #pragma unroll
    for (int j = 0; j < 8; ++j) {
      unsigned pw = z2w[WIDX(k0, g * 8 + j, cc)];
      xrb[j] = (short)(pw & 0xffff);
      xib[j] = (short)(pw >> 16);
    }
    #pragma unroll
    for (int mt = 0; mt < 2; ++mt) {
      f32x4 ar = __builtin_amdgcn_mfma_f32_16x16x32_bf16(Asn[mt], xib, az, 0, 0, 0);
      ar = __builtin_amdgcn_mfma_f32_16x16x32_bf16(Ac[mt], xrb, ar, 0, 0, 0);
      f32x4 ai = __builtin_amdgcn_mfma_f32_16x16x32_bf16(Ac[mt], xib, az, 0, 0, 0);
      ai = __builtin_amdgcn_mfma_f32_16x16x32_bf16(As[mt], xrb, ai, 0, 0, 0);
      // twiddle W_256^{c k1}, k1 = mt*16 + g*4 + r; buffer in registers
      float sb, cb, ss, cs;
      const float cf = (float)cc;
      __sincosf(-2.0f * PI_F * cf * (float)(mt * 16 + g * 4) / 256.0f, &sb, &cb);
      __sincosf(-2.0f * PI_F * cf / 256.0f, &ss, &cs);
      #pragma unroll
      for (int r = 0; r < 4; ++r) {
        float xr_ = ar[r] * cb - ai[r] * sb;
        float xi_ = ar[r] * sb + ai[r] * cb;
        unsigned pk = packbf(xr_, xi_);
        if (nt == 0) x2_0[mt][r] = pk;
        else if (nt == 1) x2_1[mt][r] = pk;
        else if (nt == 2) x2_2[mt][r] = pk;
        else x2_3[mt][r] = pk;
        float nc = cb * cs - sb * ss; sb = cb * ss + sb * cs; cb = nc;
      }
    }
  }
  __syncthreads();   // all X1 reads done -> safe to overwrite with X2

  // write X2[p][c] (p = k1*32 + k0) with R5's verified swizzle
  #pragma unroll
  for (int nt = 0; nt < 4; ++nt) {
    const int n2 = w * 64 + nt * 16 + lc;
    const int k0 = n2 >> 3, cc = n2 & 7;
    #pragma unroll
    for (int mt = 0; mt < 2; ++mt)
      #pragma unroll
      for (int r = 0; r < 4; ++r) {
        const int p = (mt * 16 + g * 4 + r) * 32 + k0;
        unsigned pk = (nt == 0) ? x2_0[mt][r] : (nt == 1) ? x2_1[mt][r]
                    : (nt == 2) ? x2_2[mt][r] : x2_3[mt][r];
        z2w[(p << 3) + (cc ^ ((p >> 2) & 7))] = pk;
      }
  }
  __syncthreads();

  // ================= stage 3: DFT8 over c; k2 in {0,7} =====================
  float z0r[4], z0i[4], z7r[4], z7i[4];
  #pragma unroll
  for (int q = 0; q < 4; ++q) {
    const int p = q * 256 + tid;
    float s0r = 0.f, s0i = 0.f, s7r = 0.f, s7i = 0.f;
    #pragma unroll
    for (int c2 = 0; c2 < 8; ++c2) {
      unsigned pw = z2w[(p << 3) + (c2 ^ ((p >> 2) & 7))];
      float vr = bff((unsigned short)(pw & 0xffff));
      float vi = bff((unsigned short)(pw >> 16));
      s0r += vr; s0i += vi;
      s7r += vr * E8C[c2] - vi * E8S[c2];
      s7i += vr * E8S[c2] + vi * E8C[c2];
    }
    z0r[q] = s0r; z0i[q] = s0i; z7r[q] = s7r; z7i[q] = s7i;
  }
  __syncthreads();   // all stage-3 reads done
  float2* zf = (float2*)z2w;   // fp32 result region: 2048 float2 = 16 KB
  #pragma unroll
  for (int q = 0; q < 4; ++q) {
    const int p = q * 256 + tid;
    zf[p]        = make_float2(z0r[q], z0i[q]);   // Z[p], p in [0,1024)
    zf[1024 + p] = make_float2(z7r[q], z7i[q]);   // Z[7168+p]
  }
  __syncthreads();

  // ---- unpack packed real FFTs -> psd (bf16), zero-pad to PSD_LDA
  for (int k = tid; k < PSD_LDA / 2; k += 256) {
    if (k < NBINS) {
      float2 Zk = zf[k];
      float2 Zn = (k == 0) ? zf[0] : zf[2048 - k];   // Z[8192-k]
      float fxr = 0.5f * (Zk.x + Zn.x);
      float fxi = 0.5f * (Zk.y - Zn.y);
      float fyr = 0.5f * (Zk.y + Zn.y);
      float fyi = 0.5f * (Zn.x - Zk.x);
      psd[(size_t)blockIdx.x * PSD_LDA + 2*k]     = __float2bfloat16(fxr*fxr + fxi*fxi);
      psd[(size_t)blockIdx.x * PSD_LDA + 2*k + 1] = __float2bfloat16(fyr*fyr + fyi*fyi);
    } else {
      psd[(size_t)blockIdx.x * PSD_LDA + 2*k]     = __float2bfloat16(0.0f);
      psd[(size_t)blockIdx.x * PSD_LDA + 2*k + 1] = __float2bfloat16(0.0f);
    }
  }

  // ---- v_mean and winding
  #pragma unroll
  for (int o = 32; o; o >>= 1) {
    vs0 += __shfl_down(vs0, o);
    vs1 += __shfl_down(vs1, o);
  }
  if ((tid & 63) == 0) { rsum[0][tid >> 6] = vs0; rsum[1][tid >> 6] = vs1; }
  __syncthreads();
  if (tid == 0) {
    float s0 = rsum[0][0] + rsum[0][1] + rsum[0][2] + rsum[0][3];
    float s1v = rsum[1][0] + rsum[1][1] + rsum[1][2] + rsum[1][3];
    vmean[blockIdx.x] = make_float2(s0 / (float)T_LEN, s1v / (float)T_LEN);
    const float inv2pi = 0.15915494309189535f;
    wind[blockIdx.x] = make_float2(fabsf(rintf((phb[2] - phb[0]) * inv2pi)),
                                   fabsf(rintf((phb[3] - phb[1]) * inv2pi)));
  }
}

// ---------------------------------------------------------------------------
// Kernel 3: C = A * A^T, A (1024 x K bf16, stride LDA), MFMA 16x16x32 bf16.
// ---------------------------------------------------------------------------
template<int K, int LDA>
__global__ __launch_bounds__(256) void gram_mfma_kernel(
    const __hip_bfloat16* __restrict__ A, float* __restrict__ C) {
  __shared__ __align__(16) __hip_bfloat16 lds[2][64][64];  // 16 KB
  const int tid  = threadIdx.x;
  const int lane = tid & 63;
  const int wave = tid >> 6;
  const int wm = wave >> 1, wn = wave & 1;
  const int i0 = blockIdx.y * 64;
  const int j0 = blockIdx.x * 64;

  f32x4 acc[2][2] = {};

  for (int k0 = 0; k0 < K; k0 += 64) {
    #pragma unroll
    for (int r = 0; r < 2; ++r) {
      int e   = tid + 256 * r;
      int row = e >> 3;
      int cb  = e & 7;
      int scb = cb ^ (row & 7);
      const __hip_bfloat16* srcA = A + (size_t)(i0 + row) * LDA + k0 + scb * 8;
      const __hip_bfloat16* srcB = A + (size_t)(j0 + row) * LDA + k0 + scb * 8;
      __builtin_amdgcn_global_load_lds(
          (const __attribute__((address_space(1))) void*)srcA,
          (__attribute__((address_space(3))) void*)(&lds[0][0][0] + e * 8),
          16, 0, 0);
      __builtin_amdgcn_global_load_lds(
          (const __attribute__((address_space(1))) void*)srcB,
          (__attribute__((address_space(3))) void*)(&lds[1][0][0] + e * 8),
          16, 0, 0);
    }
    __syncthreads();

    #pragma unroll
    for (int ks = 0; ks < 2; ++ks) {
      bf16x8 afr[2], bfr[2];
      #pragma unroll
      for (int m = 0; m < 2; ++m) {
        int row = wm * 32 + m * 16 + (lane & 15);
        int cidx = ks * 4 + (lane >> 4);
        int cc  = cidx ^ (row & 7);
        afr[m] = *(const bf16x8*)(&lds[0][row][cc * 8]);
      }
      #pragma unroll
      for (int n = 0; n < 2; ++n) {
        int row = wn * 32 + n * 16 + (lane & 15);
        int cidx = ks * 4 + (lane >> 4);
        int cc  = cidx ^ (row & 7);
        bfr[n] = *(const bf16x8*)(&lds[1][row][cc * 8]);
      }
      #pragma unroll
      for (int m = 0; m < 2; ++m)
        #pragma unroll
        for (int n = 0; n < 2; ++n)
          acc[m][n] = __builtin_amdgcn_mfma_f32_16x16x32_bf16(
              afr[m], bfr[n], acc[m][n], 0, 0, 0);
    }
    __syncthreads();
  }

  #pragma unroll
  for (int m = 0; m < 2; ++m)
    #pragma unroll
    for (int n = 0; n < 2; ++n)
      #pragma unroll
      for (int r = 0; r < 4; ++r) {
        int row = i0 + wm * 32 + m * 16 + (lane >> 4) * 4 + r;
        int col = j0 + wn * 32 + n * 16 + (lane & 15);
        C[(size_t)row * B_SZ + col] = acc[m][n][r];
      }
}

// ---------------------------------------------------------------------------
// Kernel 4: per-row loss. One block per row i.
// ---------------------------------------------------------------------------
__global__ __launch_bounds__(256) void loss_rows_kernel(
    const float* __restrict__ S,
    const float* __restrict__ G,
    const float* __restrict__ labels,
    const float* __restrict__ scales,
    const float2* __restrict__ vmean,
    const float2* __restrict__ wind,
    float* __restrict__ row_loss) {
  const int i = blockIdx.x;
  const int tid = threadIdx.x;
  const float inv_scale = 1.0f / scales[0];
  const float l0 = labels[i*3+0], l1 = labels[i*3+1], l2 = labels[i*3+2];
  const float2 vmi = vmean[i];
  const float2 wi  = wind[i];
  const float n2i  = G[(size_t)i * B_SZ + i];
  const float normi = sqrtf(n2i);

  float posw = 0.f, den = 0.f;
  for (int j = tid; j < B_SZ; j += 256) {
    if (j == i) continue;
    float e = __expf(S[(size_t)i * B_SZ + j] * 10.0f);
    den += e;

    float d0 = (labels[j*3+0] - l0) * inv_scale;
    float d1 = (labels[j*3+1] - l1) * inv_scale;
    float d2v = (labels[j*3+2] - l2) * inv_scale;
    float pd = sqrtf(d0*d0 + d1*d1 + d2v*d2v);
    float pw = __expf(-pd * 10.0f);

    float2 vmj = vmean[j];
    float dvx = vmi.x - vmj.x, dvy = vmi.y - vmj.y;
    float v_sim = __expf(-sqrtf(dvx*dvx + dvy*dvy) * 2.0f);

    float n2j = G[(size_t)j * B_SZ + j];
    float g   = G[(size_t)i * B_SZ + j];
    float dd  = fmaxf(n2i + n2j - 2.0f * g, 0.0f);
    float psd_dist = sqrtf(dd);
    float norma = (i < j) ? normi : sqrtf(n2j);
    float psd_sim = __expf(-psd_dist / (norma + 1e-8f));

    float2 wj = wind[j];
    float w_sim = (wi.x == wj.x && wi.y == wj.y) ? 1.0f : 0.0f;

    float kin = 0.4f * v_sim + 0.4f * psd_sim + 0.2f * w_sim;
    posw += e * pw * kin;
  }

  #pragma unroll
  for (int o = 32; o; o >>= 1) {
    posw += __shfl_down(posw, o);
    den  += __shfl_down(den, o);
  }
  __shared__ float bp[4], bd[4];
  if ((tid & 63) == 0) { bp[tid >> 6] = posw; bd[tid >> 6] = den; }
  __syncthreads();
  if (tid == 0) {
    float P = bp[0] + bp[1] + bp[2] + bp[3];
    float D = bd[0] + bd[1] + bd[2] + bd[3];
    row_loss[i] = -logf((P + 1e-8f) / (D + 1e-8f));
  }
}

// ---------------------------------------------------------------------------
// Kernel 5: mean of row losses -> scalar
// ---------------------------------------------------------------------------
__global__ __launch_bounds__(256) void reduce_mean_kernel(
    const float* __restrict__ row_loss, float* __restrict__ out) {
  int tid = threadIdx.x;
  float s = 0.f;
  for (int i = tid; i < B_SZ; i += 256) s += row_loss[i];
  #pragma unroll
  for (int o = 32; o; o >>= 1) s += __shfl_down(s, o);
  __shared__ float buf[4];
  if ((tid & 63) == 0) buf[tid >> 6] = s;
  __syncthreads();
  if (tid == 0) out[0] = (buf[0] + buf[1] + buf[2] + buf[3]) / (float)B_SZ;
}

// ---------------------------------------------------------------------------
extern "C" void kernel_launch(void* const* d_in, const int* in_sizes, int n_in,
                              void* d_out, int out_size, void* d_ws, size_t ws_size,
                              hipStream_t stream) {
  const float* features = (const float*)d_in[0];
  const float* labels   = (const float*)d_in[1];
  const float* traj     = (const float*)d_in[2];
  const float* scales   = (const float*)d_in[3];

  char* ws = (char*)d_ws;
  __hip_bfloat16* f_n = (__hip_bfloat16*)ws;
  __hip_bfloat16* psd = (__hip_bfloat16*)(ws + (size_t)B_SZ*256*2);
  float* G = (float*)(ws + (size_t)B_SZ*256*2 + (size_t)B_SZ*PSD_LDA*2);
  float* S = G + (size_t)B_SZ * B_SZ;
  float2* vmean = (float2*)(S + (size_t)B_SZ * B_SZ);
  float2* wind  = vmean + B_SZ;
  float* row_loss = (float*)(wind + B_SZ);

  normalize_kernel<<<B_SZ, 256, 0, stream>>>(features, f_n);
  traj_stats_kernel<<<B_SZ, 256, 0, stream>>>(traj, psd, vmean, wind);

  dim3 grid16(16, 16);
  gram_mfma_kernel<PSD_LDA, PSD_LDA><<<grid16, 256, 0, stream>>>(psd, G);
  gram_mfma_kernel<256, 256><<<grid16, 256, 0, stream>>>(f_n, S);

  loss_rows_kernel<<<B_SZ, 256, 0, stream>>>(S, G, labels, scales, vmean, wind, row_loss);
  reduce_mean_kernel<<<1, 256, 0, stream>>>(row_loss, (float*)d_out);
}